// Round 3
// baseline (640.351 us; speedup 1.0000x reference)
//
#include <hip/hip_runtime.h>
#include <hip/hip_bf16.h>

// Fused SE(3) feedforward, bf16 MFMA, fp32 accumulate.
// Round 3: round-1 proven barrier structure (2 bars/chunk, no setprio, no
// dbuf) + cheap gelu (rsq + exp tanh-form) + CH=256 fat chunks (9 barriers
// total) + scale/bias prefetch.

typedef __attribute__((ext_vector_type(8))) short short8;   // 8 bf16 = 4 VGPRs (MFMA A/B frag)
typedef __attribute__((ext_vector_type(4))) float f32x4;    // MFMA C/D frag

static __device__ __forceinline__ short f2bf(float f) {
  union { float f; unsigned u; } v; v.f = f;
  unsigned r = v.u + 0x7fffu + ((v.u >> 16) & 1u);  // RNE
  return (short)(r >> 16);
}

// ---- weight packing into MFMA-fragment order (bf16) ----
// w_in: [256 d][1024 h] -> frag tile (nt<64, kt<8): elem j of lane l is
//   w_in[kt*32 + (l>>4)*8 + j][nt*16 + (l&15)], flat = ((nt*8+kt)*64+l)*8+j
__global__ void pack_win_k(const float* __restrict__ w, short* __restrict__ p) {
  const int gid = blockIdx.x * 256 + threadIdx.x;  // 32768 total
  const int lane = gid & 63;
  const int tile = gid >> 6;
  const int kt = tile & 7, nt = tile >> 3;
  const int gg = lane >> 4, cc = lane & 15;
  short8 v;
#pragma unroll
  for (int j = 0; j < 8; ++j) {
    const int d = kt * 32 + gg * 8 + j;
    const int h = nt * 16 + cc;
    v[j] = f2bf(w[d * 1024 + h]);
  }
  *reinterpret_cast<short8*>(p + gid * 8) = v;
}

// w_out: [1024 h][256 d] -> frag tile (kt2<32, nt2<16): elem j of lane l is
//   w_out[kt2*32 + (l>>4)*8 + j][nt2*16 + (l&15)], flat = ((kt2*16+nt2)*64+l)*8+j
__global__ void pack_wout_k(const float* __restrict__ w, short* __restrict__ p) {
  const int gid = blockIdx.x * 256 + threadIdx.x;  // 32768 total
  const int lane = gid & 63;
  const int tile = gid >> 6;
  const int nt2 = tile & 15, kt2 = tile >> 4;
  const int gg = lane >> 4, cc = lane & 15;
  short8 v;
#pragma unroll
  for (int j = 0; j < 8; ++j) {
    const int h = kt2 * 32 + gg * 8 + j;
    const int d = nt2 * 16 + cc;
    v[j] = f2bf(w[h * 256 + d]);
  }
  *reinterpret_cast<short8*>(p + gid * 8) = v;
}

// ---- fused main kernel ----
// Tokens t = mm*16 + r (m-major): the mm-group of a (row,h) pair shares
// (lane, reg) across M-tile accumulators -> norm/gelu fully in-register.
// LDS XOR swizzle: byte ^= (t&7)<<4 (both lA and lH are [t][256] bf16).
template<int M, int MINW>
__global__ __launch_bounds__(256, MINW)
void ff_se3_kernel(const float* __restrict__ x,
                   const short* __restrict__ wpin,
                   const short* __restrict__ wpout,
                   const float* __restrict__ scale,
                   const float* __restrict__ bias,
                   float* __restrict__ out)
{
  constexpr int T = 16 * M;
  __shared__ short lA[T * 256];  // x tokens bf16, [t][256 d], swizzled
  __shared__ short lH[T * 256];  // gated h chunk bf16, [t][256], swizzled

  const int tid  = threadIdx.x;
  const int lane = tid & 63;
  const int wave = tid >> 6;
  const int g    = lane >> 4;
  const int lc   = lane & 15;
  const long row0 = (long)blockIdx.x * 16;

  // stage x -> lA (read coalesced float4, scatter bf16 into token layout)
  for (int e4 = tid; e4 < 16 * 64 * M; e4 += 256) {
    const int r  = e4 / (64 * M);
    const int o4 = e4 - r * (64 * M);
    const float4 v = *reinterpret_cast<const float4*>(x + (row0 + r) * (256 * M) + o4 * 4);
    const float vv[4] = {v.x, v.y, v.z, v.w};
#pragma unroll
    for (int i = 0; i < 4; ++i) {
      const int flat = o4 * 4 + i;
      const int d  = flat / M;
      const int mm = flat - d * M;
      const int t  = mm * 16 + r;
      const int byte = t * 512 + ((d * 2) ^ ((t & 7) << 4));
      lA[byte >> 1] = f2bf(vv[i]);
    }
  }

  f32x4 acc_out[M][4];
#pragma unroll
  for (int a = 0; a < M; ++a)
#pragma unroll
    for (int b = 0; b < 4; ++b) acc_out[a][b] = (f32x4)(0.f);

  __syncthreads();

  for (int c = 0; c < 4; ++c) {   // 256-h chunks
    // prefetch this chunk's scale/bias (hidden under GEMM1)
    float sc4[4], bi4[4];
#pragma unroll
    for (int nn = 0; nn < 4; ++nn) {
      const int hgl = c * 256 + wave * 64 + nn * 16 + lc;
      sc4[nn] = scale[hgl];
      bi4[nn] = bias[hgl];
    }

    // ---- GEMM1: this wave owns 64 h-cols (4 n-tiles), K=256 ----
    f32x4 acc1[M][4];
#pragma unroll
    for (int a = 0; a < M; ++a)
#pragma unroll
      for (int b = 0; b < 4; ++b) acc1[a][b] = (f32x4)(0.f);
#pragma unroll
    for (int kt = 0; kt < 8; ++kt) {
      short8 af[M];
#pragma unroll
      for (int mm = 0; mm < M; ++mm) {
        const int t = mm * 16 + lc;
        const int byte = t * 512 + (((kt * 32 + g * 8) * 2) ^ ((t & 7) << 4));
        af[mm] = *reinterpret_cast<const short8*>(&lA[byte >> 1]);
      }
      short8 bfr[4];
#pragma unroll
      for (int nn = 0; nn < 4; ++nn) {
        const int ntg = c * 16 + wave * 4 + nn;
        bfr[nn] = *reinterpret_cast<const short8*>(wpin + ((ntg * 8 + kt) * 64 + lane) * 8);
      }
#pragma unroll
      for (int mm = 0; mm < M; ++mm)
#pragma unroll
        for (int nn = 0; nn < 4; ++nn)
          acc1[mm][nn] = __builtin_amdgcn_mfma_f32_16x16x32_bf16(af[mm], bfr[nn], acc1[mm][nn], 0, 0, 0);
    }

    __syncthreads();

    // ---- nonlinearity: per (row,h) norm over mm + tanh-form gelu gate ----
#pragma unroll
    for (int nn = 0; nn < 4; ++nn) {
      const float sc = sc4[nn];
      const float bi = bi4[nn];
#pragma unroll
      for (int reg = 0; reg < 4; ++reg) {
        float ns = 0.f;
#pragma unroll
        for (int mm = 0; mm < M; ++mm) ns += acc1[mm][nn][reg] * acc1[mm][nn][reg];
        ns = fmaxf(ns, 1e-24f);
        const float rn  = __builtin_amdgcn_rsqf(ns);    // v_rsq_f32
        const float nrm = ns * rn;                       // ||h||
        const float z   = fmaf(nrm, sc, bi);
        float u2 = 2.f * z * fmaf(0.0356774081f * z, z, 0.7978845608f);
        u2 = fminf(u2, 30.f);                            // overflow guard
        const float e  = __expf(u2);                     // v_exp_f32
        const float th = (e - 1.f) * __builtin_amdgcn_rcpf(e + 1.f);  // tanh(u2/2)
        const float fac = 0.5f * (1.f + th) * z * rn;    // gate/||h||
        const int tl  = g * 4 + reg;                     // C-layout row
        const int col = wave * 64 + nn * 16 + lc;
#pragma unroll
        for (int mm = 0; mm < M; ++mm) {
          const int t = mm * 16 + tl;
          const int byte = t * 512 + ((col * 2) ^ ((t & 7) << 4));
          lH[byte >> 1] = f2bf(acc1[mm][nn][reg] * fac);
        }
      }
    }

    __syncthreads();

    // ---- GEMM2 partial: acc_out += hg[T,256] @ w_out[chunk,256] ----
#pragma unroll
    for (int kk = 0; kk < 8; ++kk) {
      short8 a2[M];
#pragma unroll
      for (int mm = 0; mm < M; ++mm) {
        const int t = mm * 16 + lc;
        const int byte = t * 512 + (((kk * 32 + g * 8) * 2) ^ ((t & 7) << 4));
        a2[mm] = *reinterpret_cast<const short8*>(&lH[byte >> 1]);
      }
      short8 b2[4];
#pragma unroll
      for (int nn = 0; nn < 4; ++nn) {
        const int tile = (c * 8 + kk) * 16 + wave * 4 + nn;
        b2[nn] = *reinterpret_cast<const short8*>(wpout + (tile * 64 + lane) * 8);
      }
#pragma unroll
      for (int mm = 0; mm < M; ++mm)
#pragma unroll
        for (int nn = 0; nn < 4; ++nn)
          acc_out[mm][nn] = __builtin_amdgcn_mfma_f32_16x16x32_bf16(a2[mm], b2[nn], acc_out[mm][nn], 0, 0, 0);
    }
    // no loop-end barrier needed: next nonlin's lH writes are after the next
    // BAR_A, which all GEMM2(c) readers must reach first (round-1-proven).
  }

  // epilogue: C-layout (col=lane&15, row=(lane>>4)*4+reg), token = mm*16+row
#pragma unroll
  for (int mm = 0; mm < M; ++mm)
#pragma unroll
    for (int nn = 0; nn < 4; ++nn) {
      const int d = wave * 64 + nn * 16 + lc;
#pragma unroll
      for (int reg = 0; reg < 4; ++reg) {
        const int r = g * 4 + reg;
        out[((row0 + r) * 256 + d) * M + mm] = acc_out[mm][nn][reg];
      }
    }
}

extern "C" void kernel_launch(void* const* d_in, const int* in_sizes, int n_in,
                              void* d_out, int out_size, void* d_ws, size_t ws_size,
                              hipStream_t stream)
{
  // d_in order per setup_inputs: (x, w_in, scale, bias, w_out) x degree 0..2
  short* ws = (short*)d_ws;                 // needs 6 * 512KB = 3MB
  const size_t WSZ = 256 * 1024;            // shorts per packed matrix
  float* outf = (float*)d_out;
  const size_t out_off[3] = {0, 4194304, 16777216};  // y0|y1|y2 concat (m=1,3,5)

  for (int dg = 0; dg < 3; ++dg) {
    const float* w_in  = (const float*)d_in[5 * dg + 1];
    const float* w_out = (const float*)d_in[5 * dg + 4];
    pack_win_k <<<128, 256, 0, stream>>>(w_in,  ws + (2 * dg) * WSZ);
    pack_wout_k<<<128, 256, 0, stream>>>(w_out, ws + (2 * dg + 1) * WSZ);
  }
  for (int dg = 0; dg < 3; ++dg) {
    const float* x  = (const float*)d_in[5 * dg + 0];
    const float* sc = (const float*)d_in[5 * dg + 2];
    const float* bi = (const float*)d_in[5 * dg + 3];
    const short* pin  = ws + (2 * dg) * WSZ;
    const short* pout = ws + (2 * dg + 1) * WSZ;
    float* o = outf + out_off[dg];
    switch (dg) {
      case 0: ff_se3_kernel<1, 4><<<1024, 256, 0, stream>>>(x, pin, pout, sc, bi, o); break;
      case 1: ff_se3_kernel<3, 2><<<1024, 256, 0, stream>>>(x, pin, pout, sc, bi, o); break;
      case 2: ff_se3_kernel<5, 2><<<1024, 256, 0, stream>>>(x, pin, pout, sc, bi, o); break;
    }
  }
}

// Round 4
// 319.792 us; speedup vs baseline: 2.0024x; 2.0024x over previous
//
#include <hip/hip_runtime.h>
#include <hip/hip_bf16.h>

// Fused SE(3) feedforward, bf16 MFMA, fp32 accumulate.
// Round 4: round-1 CH=128 structure (no spill) + cheap gelu + non-temporal
// x/y streaming (protect weight set in L2/L3) + LDS-staged coalesced epilogue.

typedef __attribute__((ext_vector_type(8))) short short8;   // 8 bf16 = 4 VGPRs (MFMA A/B frag)
typedef __attribute__((ext_vector_type(4))) float f32x4;    // MFMA C/D frag

static __device__ __forceinline__ short f2bf(float f) {
  union { float f; unsigned u; } v; v.f = f;
  unsigned r = v.u + 0x7fffu + ((v.u >> 16) & 1u);  // RNE
  return (short)(r >> 16);
}

// ---- weight packing into MFMA-fragment order (bf16) ----
// w_in: [256 d][1024 h] -> frag tile (nt<64, kt<8): elem j of lane l is
//   w_in[kt*32 + (l>>4)*8 + j][nt*16 + (l&15)], flat = ((nt*8+kt)*64+l)*8+j
__global__ void pack_win_k(const float* __restrict__ w, short* __restrict__ p) {
  const int gid = blockIdx.x * 256 + threadIdx.x;  // 32768 total
  const int lane = gid & 63;
  const int tile = gid >> 6;
  const int kt = tile & 7, nt = tile >> 3;
  const int gg = lane >> 4, cc = lane & 15;
  short8 v;
#pragma unroll
  for (int j = 0; j < 8; ++j) {
    const int d = kt * 32 + gg * 8 + j;
    const int h = nt * 16 + cc;
    v[j] = f2bf(w[d * 1024 + h]);
  }
  *reinterpret_cast<short8*>(p + gid * 8) = v;
}

// w_out: [1024 h][256 d] -> frag tile (kt2<32, nt2<16): elem j of lane l is
//   w_out[kt2*32 + (l>>4)*8 + j][nt2*16 + (l&15)], flat = ((kt2*16+nt2)*64+l)*8+j
__global__ void pack_wout_k(const float* __restrict__ w, short* __restrict__ p) {
  const int gid = blockIdx.x * 256 + threadIdx.x;  // 32768 total
  const int lane = gid & 63;
  const int tile = gid >> 6;
  const int nt2 = tile & 15, kt2 = tile >> 4;
  const int gg = lane >> 4, cc = lane & 15;
  short8 v;
#pragma unroll
  for (int j = 0; j < 8; ++j) {
    const int h = kt2 * 32 + gg * 8 + j;
    const int d = nt2 * 16 + cc;
    v[j] = f2bf(w[h * 256 + d]);
  }
  *reinterpret_cast<short8*>(p + gid * 8) = v;
}

// ---- fused main kernel ----
// Tokens t = mm*16 + r (m-major): the mm-group of a (row,h) pair shares
// (lane, reg) across M-tile accumulators -> norm/gelu fully in-register.
// LDS XOR swizzle: byte ^= (t&7)<<4.
template<int M>
__global__ __launch_bounds__(256, 2)
void ff_se3_kernel(const float* __restrict__ x,
                   const short* __restrict__ wpin,
                   const short* __restrict__ wpout,
                   const float* __restrict__ scale,
                   const float* __restrict__ bias,
                   float* __restrict__ out)
{
  constexpr int T = 16 * M;
  // union LDS: lA = lds[0 .. 4096M), lH = lds[4096M .. 6144M)
  // epilogue overlays the whole array as float scratch (needs 4096M shorts)
  __shared__ short lds[6144 * M];
  short* lA = lds;
  short* lH = lds + 4096 * M;

  const int tid  = threadIdx.x;
  const int lane = tid & 63;
  const int wave = tid >> 6;
  const int g    = lane >> 4;
  const int lc   = lane & 15;
  const long row0 = (long)blockIdx.x * 16;

  // stage x -> lA (nt float4 reads, scatter bf16 into token layout)
  for (int e4 = tid; e4 < 16 * 64 * M; e4 += 256) {
    const int r  = e4 / (64 * M);
    const int o4 = e4 - r * (64 * M);
    const f32x4 v = __builtin_nontemporal_load(
        reinterpret_cast<const f32x4*>(x + (row0 + r) * (256 * M) + o4 * 4));
#pragma unroll
    for (int i = 0; i < 4; ++i) {
      const int flat = o4 * 4 + i;
      const int d  = flat / M;
      const int mm = flat - d * M;
      const int t  = mm * 16 + r;
      const int byte = t * 512 + ((d * 2) ^ ((t & 7) << 4));
      lA[byte >> 1] = f2bf(v[i]);
    }
  }

  f32x4 acc_out[M][4];
#pragma unroll
  for (int a = 0; a < M; ++a)
#pragma unroll
    for (int b = 0; b < 4; ++b) acc_out[a][b] = (f32x4)(0.f);

  __syncthreads();

  for (int c = 0; c < 8; ++c) {   // 128-h chunks
    // prefetch this chunk's scale/bias (hidden under GEMM1)
    float sc2[2], bi2[2];
#pragma unroll
    for (int nn = 0; nn < 2; ++nn) {
      const int hgl = c * 128 + wave * 32 + nn * 16 + lc;
      sc2[nn] = scale[hgl];
      bi2[nn] = bias[hgl];
    }

    // ---- GEMM1: this wave owns 32 h-cols (2 n-tiles), K=256 ----
    f32x4 acc1[M][2];
#pragma unroll
    for (int a = 0; a < M; ++a) { acc1[a][0] = (f32x4)(0.f); acc1[a][1] = (f32x4)(0.f); }
#pragma unroll
    for (int kt = 0; kt < 8; ++kt) {
      short8 af[M];
#pragma unroll
      for (int mm = 0; mm < M; ++mm) {
        const int t = mm * 16 + lc;
        const int byte = t * 512 + (((kt * 32 + g * 8) * 2) ^ ((t & 7) << 4));
        af[mm] = *reinterpret_cast<const short8*>(&lA[byte >> 1]);
      }
      short8 bfr[2];
#pragma unroll
      for (int nn = 0; nn < 2; ++nn) {
        const int ntg = c * 8 + wave * 2 + nn;
        bfr[nn] = *reinterpret_cast<const short8*>(wpin + ((ntg * 8 + kt) * 64 + lane) * 8);
      }
#pragma unroll
      for (int mm = 0; mm < M; ++mm)
#pragma unroll
        for (int nn = 0; nn < 2; ++nn)
          acc1[mm][nn] = __builtin_amdgcn_mfma_f32_16x16x32_bf16(af[mm], bfr[nn], acc1[mm][nn], 0, 0, 0);
    }

    __syncthreads();

    // ---- nonlinearity: per (row,h) norm over mm + tanh-form gelu gate ----
#pragma unroll
    for (int nn = 0; nn < 2; ++nn) {
      const float sc = sc2[nn];
      const float bi = bi2[nn];
#pragma unroll
      for (int reg = 0; reg < 4; ++reg) {
        float ns = 0.f;
#pragma unroll
        for (int mm = 0; mm < M; ++mm) ns += acc1[mm][nn][reg] * acc1[mm][nn][reg];
        ns = fmaxf(ns, 1e-24f);
        const float rn  = __builtin_amdgcn_rsqf(ns);    // v_rsq_f32
        const float nrm = ns * rn;                       // ||h||
        const float z   = fmaf(nrm, sc, bi);
        float u2 = 2.f * z * fmaf(0.0356774081f * z, z, 0.7978845608f);
        u2 = fminf(u2, 30.f);                            // overflow guard
        const float e  = __expf(u2);                     // v_exp_f32
        const float th = (e - 1.f) * __builtin_amdgcn_rcpf(e + 1.f);  // tanh(u2/2)
        const float fac = 0.5f * (1.f + th) * z * rn;    // gate/||h||
        const int tl  = g * 4 + reg;                     // C-layout row
        const int col = wave * 32 + nn * 16 + lc;
#pragma unroll
        for (int mm = 0; mm < M; ++mm) {
          const int t = mm * 16 + tl;
          const int byte = t * 256 + ((col * 2) ^ ((t & 7) << 4));
          lH[byte >> 1] = f2bf(acc1[mm][nn][reg] * fac);
        }
      }
    }

    __syncthreads();

    // ---- GEMM2 partial: acc_out += hg[T,128] @ w_out[chunk,256] ----
#pragma unroll
    for (int kk = 0; kk < 4; ++kk) {
      short8 a2[M];
#pragma unroll
      for (int mm = 0; mm < M; ++mm) {
        const int t = mm * 16 + lc;
        const int byte = t * 256 + (((kk * 32 + g * 8) * 2) ^ ((t & 7) << 4));
        a2[mm] = *reinterpret_cast<const short8*>(&lH[byte >> 1]);
      }
      short8 b2[4];
#pragma unroll
      for (int nn = 0; nn < 4; ++nn) {
        const int tile = (c * 4 + kk) * 16 + wave * 4 + nn;
        b2[nn] = *reinterpret_cast<const short8*>(wpout + (tile * 64 + lane) * 8);
      }
#pragma unroll
      for (int mm = 0; mm < M; ++mm)
#pragma unroll
        for (int nn = 0; nn < 4; ++nn)
          acc_out[mm][nn] = __builtin_amdgcn_mfma_f32_16x16x32_bf16(a2[mm], b2[nn], acc_out[mm][nn], 0, 0, 0);
    }
    // no loop-end barrier needed: next nonlin's lH writes are after the next
    // BAR_A, which all GEMM2(c) readers must reach first (round-1-proven).
  }

  // ---- epilogue: stage [8 rows][256*M] fp32 in LDS, store coalesced nt ----
  float* ldsF = reinterpret_cast<float*>(lds);
  const int RW = 256 * M;            // floats per output row
#pragma unroll
  for (int half = 0; half < 2; ++half) {
    __syncthreads();                 // lA/lH readers done (or prev half stored)
    if ((g >> 1) == half) {          // rows half*8 .. half*8+7 live in g=2h,2h+1
#pragma unroll
      for (int nn = 0; nn < 4; ++nn) {
        const int d = wave * 64 + nn * 16 + lc;
#pragma unroll
        for (int reg = 0; reg < 4; ++reg) {
          const int rloc = (g & 1) * 4 + reg;   // 0..7
#pragma unroll
          for (int mm = 0; mm < M; ++mm)
            ldsF[rloc * RW + d * M + mm] = acc_out[mm][nn][reg];
        }
      }
    }
    __syncthreads();
    const int nf4 = 2 * RW;          // (8*RW)/4 float4s
    for (int i = tid; i < nf4; i += 256) {
      const f32x4 v = *reinterpret_cast<const f32x4*>(&ldsF[i * 4]);
      const int rloc = (i * 4) / RW;
      const int off  = (i * 4) - rloc * RW;
      __builtin_nontemporal_store(v,
          reinterpret_cast<f32x4*>(out + (row0 + half * 8 + rloc) * RW + off));
    }
  }
}

extern "C" void kernel_launch(void* const* d_in, const int* in_sizes, int n_in,
                              void* d_out, int out_size, void* d_ws, size_t ws_size,
                              hipStream_t stream)
{
  // d_in order per setup_inputs: (x, w_in, scale, bias, w_out) x degree 0..2
  short* ws = (short*)d_ws;                 // needs 6 * 512KB = 3MB
  const size_t WSZ = 256 * 1024;            // shorts per packed matrix
  float* outf = (float*)d_out;
  const size_t out_off[3] = {0, 4194304, 16777216};  // y0|y1|y2 concat (m=1,3,5)

  for (int dg = 0; dg < 3; ++dg) {
    const float* w_in  = (const float*)d_in[5 * dg + 1];
    const float* w_out = (const float*)d_in[5 * dg + 4];
    pack_win_k <<<128, 256, 0, stream>>>(w_in,  ws + (2 * dg) * WSZ);
    pack_wout_k<<<128, 256, 0, stream>>>(w_out, ws + (2 * dg + 1) * WSZ);
  }
  for (int dg = 0; dg < 3; ++dg) {
    const float* x  = (const float*)d_in[5 * dg + 0];
    const float* sc = (const float*)d_in[5 * dg + 2];
    const float* bi = (const float*)d_in[5 * dg + 3];
    const short* pin  = ws + (2 * dg) * WSZ;
    const short* pout = ws + (2 * dg + 1) * WSZ;
    float* o = outf + out_off[dg];
    switch (dg) {
      case 0: ff_se3_kernel<1><<<1024, 256, 0, stream>>>(x, pin, pout, sc, bi, o); break;
      case 1: ff_se3_kernel<3><<<1024, 256, 0, stream>>>(x, pin, pout, sc, bi, o); break;
      case 2: ff_se3_kernel<5><<<1024, 256, 0, stream>>>(x, pin, pout, sc, bi, o); break;
    }
  }
}

// Round 5
// 306.964 us; speedup vs baseline: 2.0861x; 1.0418x over previous
//
#include <hip/hip_runtime.h>
#include <hip/hip_bf16.h>

// Fused SE(3) feedforward, bf16 MFMA, fp32 accumulate.
// Round 5: R4 structure (proven) + single fused pack kernel (was 6 launches)
// + compiler bf16 converts (v_cvt_pk) instead of hand-rolled RNE bit-twiddle.

typedef __attribute__((ext_vector_type(8))) short short8;   // 8 bf16 = 4 VGPRs (MFMA A/B frag)
typedef __attribute__((ext_vector_type(4))) float f32x4;    // MFMA C/D frag

static __device__ __forceinline__ short f2bf(float f) {
  __hip_bfloat16 h = __float2bfloat16(f);   // RNE; compiler emits v_cvt_pk_bf16_f32
  return *reinterpret_cast<short*>(&h);
}

// ---- fused weight packing into MFMA-fragment order (bf16) ----
// region r = blockIdx.x>>7: r=2*dg+0 -> w_in(dg), r=2*dg+1 -> w_out(dg).
// w_in: [256 d][1024 h]  -> tile (nt<64, kt<8):  elem j of lane l = w_in[kt*32+(l>>4)*8+j][nt*16+(l&15)]
// w_out: [1024 h][256 d] -> tile (kt2<32,nt2<16): elem j of lane l = w_out[kt2*32+(l>>4)*8+j][nt2*16+(l&15)]
__global__ void pack_all_k(const float* __restrict__ w0i, const float* __restrict__ w0o,
                           const float* __restrict__ w1i, const float* __restrict__ w1o,
                           const float* __restrict__ w2i, const float* __restrict__ w2o,
                           short* __restrict__ p) {
  const int region = blockIdx.x >> 7;                 // 0..5
  const int gid = (blockIdx.x & 127) * 256 + threadIdx.x;  // 0..32767
  const int lane = gid & 63;
  const int tile = gid >> 6;
  const int gg = lane >> 4, cc = lane & 15;
  const float* w = (region == 0) ? w0i : (region == 1) ? w0o :
                   (region == 2) ? w1i : (region == 3) ? w1o :
                   (region == 4) ? w2i : w2o;
  short8 v;
  if (region & 1) {   // w_out pack
    const int nt2 = tile & 15, kt2 = tile >> 4;
#pragma unroll
    for (int j = 0; j < 8; ++j)
      v[j] = f2bf(w[(kt2 * 32 + gg * 8 + j) * 256 + nt2 * 16 + cc]);
  } else {            // w_in pack
    const int kt = tile & 7, nt = tile >> 3;
#pragma unroll
    for (int j = 0; j < 8; ++j)
      v[j] = f2bf(w[(kt * 32 + gg * 8 + j) * 1024 + nt * 16 + cc]);
  }
  *reinterpret_cast<short8*>(p + ((size_t)region * 262144) + gid * 8) = v;
}

// ---- fused main kernel ----
// Tokens t = mm*16 + r (m-major): the mm-group of a (row,h) pair shares
// (lane, reg) across M-tile accumulators -> norm/gelu fully in-register.
// LDS XOR swizzle: byte ^= (t&7)<<4.
template<int M>
__global__ __launch_bounds__(256, 2)
void ff_se3_kernel(const float* __restrict__ x,
                   const short* __restrict__ wpin,
                   const short* __restrict__ wpout,
                   const float* __restrict__ scale,
                   const float* __restrict__ bias,
                   float* __restrict__ out)
{
  constexpr int T = 16 * M;
  // union LDS: lA = lds[0 .. 4096M), lH = lds[4096M .. 6144M)
  // epilogue overlays the whole array as float scratch (needs 4096M shorts)
  __shared__ short lds[6144 * M];
  short* lA = lds;
  short* lH = lds + 4096 * M;

  const int tid  = threadIdx.x;
  const int lane = tid & 63;
  const int wave = tid >> 6;
  const int g    = lane >> 4;
  const int lc   = lane & 15;
  const long row0 = (long)blockIdx.x * 16;

  // stage x -> lA (nt float4 reads, scatter bf16 into token layout)
  for (int e4 = tid; e4 < 16 * 64 * M; e4 += 256) {
    const int r  = e4 / (64 * M);
    const int o4 = e4 - r * (64 * M);
    const f32x4 v = __builtin_nontemporal_load(
        reinterpret_cast<const f32x4*>(x + (row0 + r) * (256 * M) + o4 * 4));
#pragma unroll
    for (int i = 0; i < 4; ++i) {
      const int flat = o4 * 4 + i;
      const int d  = flat / M;
      const int mm = flat - d * M;
      const int t  = mm * 16 + r;
      const int byte = t * 512 + ((d * 2) ^ ((t & 7) << 4));
      lA[byte >> 1] = f2bf(v[i]);
    }
  }

  f32x4 acc_out[M][4];
#pragma unroll
  for (int a = 0; a < M; ++a)
#pragma unroll
    for (int b = 0; b < 4; ++b) acc_out[a][b] = (f32x4)(0.f);

  __syncthreads();

  for (int c = 0; c < 8; ++c) {   // 128-h chunks
    // prefetch this chunk's scale/bias (hidden under GEMM1)
    float sc2[2], bi2[2];
#pragma unroll
    for (int nn = 0; nn < 2; ++nn) {
      const int hgl = c * 128 + wave * 32 + nn * 16 + lc;
      sc2[nn] = scale[hgl];
      bi2[nn] = bias[hgl];
    }

    // ---- GEMM1: this wave owns 32 h-cols (2 n-tiles), K=256 ----
    f32x4 acc1[M][2];
#pragma unroll
    for (int a = 0; a < M; ++a) { acc1[a][0] = (f32x4)(0.f); acc1[a][1] = (f32x4)(0.f); }
#pragma unroll
    for (int kt = 0; kt < 8; ++kt) {
      short8 af[M];
#pragma unroll
      for (int mm = 0; mm < M; ++mm) {
        const int t = mm * 16 + lc;
        const int byte = t * 512 + (((kt * 32 + g * 8) * 2) ^ ((t & 7) << 4));
        af[mm] = *reinterpret_cast<const short8*>(&lA[byte >> 1]);
      }
      short8 bfr[2];
#pragma unroll
      for (int nn = 0; nn < 2; ++nn) {
        const int ntg = c * 8 + wave * 2 + nn;
        bfr[nn] = *reinterpret_cast<const short8*>(wpin + ((ntg * 8 + kt) * 64 + lane) * 8);
      }
#pragma unroll
      for (int mm = 0; mm < M; ++mm)
#pragma unroll
        for (int nn = 0; nn < 2; ++nn)
          acc1[mm][nn] = __builtin_amdgcn_mfma_f32_16x16x32_bf16(af[mm], bfr[nn], acc1[mm][nn], 0, 0, 0);
    }

    __syncthreads();

    // ---- nonlinearity: per (row,h) norm over mm + tanh-form gelu gate ----
#pragma unroll
    for (int nn = 0; nn < 2; ++nn) {
      const float sc = sc2[nn];
      const float bi = bi2[nn];
#pragma unroll
      for (int reg = 0; reg < 4; ++reg) {
        float ns = 0.f;
#pragma unroll
        for (int mm = 0; mm < M; ++mm) ns += acc1[mm][nn][reg] * acc1[mm][nn][reg];
        ns = fmaxf(ns, 1e-24f);
        const float rn  = __builtin_amdgcn_rsqf(ns);    // v_rsq_f32
        const float nrm = ns * rn;                       // ||h||
        const float z   = fmaf(nrm, sc, bi);
        float u2 = 2.f * z * fmaf(0.0356774081f * z, z, 0.7978845608f);
        u2 = fminf(u2, 30.f);                            // overflow guard
        const float e  = __expf(u2);                     // v_exp_f32
        const float th = (e - 1.f) * __builtin_amdgcn_rcpf(e + 1.f);  // tanh(u2/2)
        const float fac = 0.5f * (1.f + th) * z * rn;    // gate/||h||
        const int tl  = g * 4 + reg;                     // C-layout row
        const int col = wave * 32 + nn * 16 + lc;
#pragma unroll
        for (int mm = 0; mm < M; ++mm) {
          const int t = mm * 16 + tl;
          const int byte = t * 256 + ((col * 2) ^ ((t & 7) << 4));
          lH[byte >> 1] = f2bf(acc1[mm][nn][reg] * fac);
        }
      }
    }

    __syncthreads();

    // ---- GEMM2 partial: acc_out += hg[T,128] @ w_out[chunk,256] ----
#pragma unroll
    for (int kk = 0; kk < 4; ++kk) {
      short8 a2[M];
#pragma unroll
      for (int mm = 0; mm < M; ++mm) {
        const int t = mm * 16 + lc;
        const int byte = t * 256 + (((kk * 32 + g * 8) * 2) ^ ((t & 7) << 4));
        a2[mm] = *reinterpret_cast<const short8*>(&lH[byte >> 1]);
      }
      short8 b2[4];
#pragma unroll
      for (int nn = 0; nn < 4; ++nn) {
        const int tile = (c * 4 + kk) * 16 + wave * 4 + nn;
        b2[nn] = *reinterpret_cast<const short8*>(wpout + (tile * 64 + lane) * 8);
      }
#pragma unroll
      for (int mm = 0; mm < M; ++mm)
#pragma unroll
        for (int nn = 0; nn < 4; ++nn)
          acc_out[mm][nn] = __builtin_amdgcn_mfma_f32_16x16x32_bf16(a2[mm], b2[nn], acc_out[mm][nn], 0, 0, 0);
    }
    // no loop-end barrier needed: next nonlin's lH writes are after the next
    // BAR_A, which all GEMM2(c) readers must reach first (round-1-proven).
  }

  // ---- epilogue: stage [8 rows][256*M] fp32 in LDS, store coalesced nt ----
  float* ldsF = reinterpret_cast<float*>(lds);
  const int RW = 256 * M;            // floats per output row
#pragma unroll
  for (int half = 0; half < 2; ++half) {
    __syncthreads();                 // lA/lH readers done (or prev half stored)
    if ((g >> 1) == half) {          // rows half*8 .. half*8+7 live in g=2h,2h+1
#pragma unroll
      for (int nn = 0; nn < 4; ++nn) {
        const int d = wave * 64 + nn * 16 + lc;
#pragma unroll
        for (int reg = 0; reg < 4; ++reg) {
          const int rloc = (g & 1) * 4 + reg;   // 0..7
#pragma unroll
          for (int mm = 0; mm < M; ++mm)
            ldsF[rloc * RW + d * M + mm] = acc_out[mm][nn][reg];
        }
      }
    }
    __syncthreads();
    const int nf4 = 2 * RW;          // (8*RW)/4 float4s
    for (int i = tid; i < nf4; i += 256) {
      const f32x4 v = *reinterpret_cast<const f32x4*>(&ldsF[i * 4]);
      const int rloc = (i * 4) / RW;
      const int off  = (i * 4) - rloc * RW;
      __builtin_nontemporal_store(v,
          reinterpret_cast<f32x4*>(out + (row0 + half * 8 + rloc) * RW + off));
    }
  }
}

extern "C" void kernel_launch(void* const* d_in, const int* in_sizes, int n_in,
                              void* d_out, int out_size, void* d_ws, size_t ws_size,
                              hipStream_t stream)
{
  // d_in order per setup_inputs: (x, w_in, scale, bias, w_out) x degree 0..2
  short* ws = (short*)d_ws;                 // needs 6 * 512KB = 3MB
  const size_t WSZ = 262144;                // shorts per packed matrix
  float* outf = (float*)d_out;
  const size_t out_off[3] = {0, 4194304, 16777216};  // y0|y1|y2 concat (m=1,3,5)

  pack_all_k<<<768, 256, 0, stream>>>(
      (const float*)d_in[1],  (const float*)d_in[4],
      (const float*)d_in[6],  (const float*)d_in[9],
      (const float*)d_in[11], (const float*)d_in[14], ws);

  for (int dg = 0; dg < 3; ++dg) {
    const float* x  = (const float*)d_in[5 * dg + 0];
    const float* sc = (const float*)d_in[5 * dg + 2];
    const float* bi = (const float*)d_in[5 * dg + 3];
    const short* pin  = ws + (2 * dg) * WSZ;
    const short* pout = ws + (2 * dg + 1) * WSZ;
    float* o = outf + out_off[dg];
    switch (dg) {
      case 0: ff_se3_kernel<1><<<1024, 256, 0, stream>>>(x, pin, pout, sc, bi, o); break;
      case 1: ff_se3_kernel<3><<<1024, 256, 0, stream>>>(x, pin, pout, sc, bi, o); break;
      case 2: ff_se3_kernel<5><<<1024, 256, 0, stream>>>(x, pin, pout, sc, bi, o); break;
    }
  }
}

// Round 6
// 266.751 us; speedup vs baseline: 2.4006x; 1.1508x over previous
//
#include <hip/hip_runtime.h>
#include <hip/hip_bf16.h>

// Fused SE(3) feedforward, bf16 MFMA, fp32 accumulate.
// Round 6: lH double-buffer -> 1 barrier/chunk (9 total), dynamic LDS,
// M=1 at 32 rows/block (NT=2, per-tile norm), GEMM2 B-frag prefetch,
// single-pass contiguous epilogue.

typedef __attribute__((ext_vector_type(8))) short short8;   // 8 bf16 (MFMA A/B frag)
typedef __attribute__((ext_vector_type(4))) float f32x4;    // MFMA C/D frag

static __device__ __forceinline__ short f2bf(float f) {
  __hip_bfloat16 h = __float2bfloat16(f);
  return *reinterpret_cast<short*>(&h);
}

// ---- fused weight packing into MFMA-fragment order (bf16) ----
// region r = blockIdx.x>>7: r=2*dg+0 -> w_in(dg), r=2*dg+1 -> w_out(dg).
__global__ void pack_all_k(const float* __restrict__ w0i, const float* __restrict__ w0o,
                           const float* __restrict__ w1i, const float* __restrict__ w1o,
                           const float* __restrict__ w2i, const float* __restrict__ w2o,
                           short* __restrict__ p) {
  const int region = blockIdx.x >> 7;                 // 0..5
  const int gid = (blockIdx.x & 127) * 256 + threadIdx.x;  // 0..32767
  const int lane = gid & 63;
  const int tile = gid >> 6;
  const int gg = lane >> 4, cc = lane & 15;
  const float* w = (region == 0) ? w0i : (region == 1) ? w0o :
                   (region == 2) ? w1i : (region == 3) ? w1o :
                   (region == 4) ? w2i : w2o;
  short8 v;
  if (region & 1) {   // w_out pack: tile (kt2<32, nt2<16)
    const int nt2 = tile & 15, kt2 = tile >> 4;
#pragma unroll
    for (int j = 0; j < 8; ++j)
      v[j] = f2bf(w[(kt2 * 32 + gg * 8 + j) * 256 + nt2 * 16 + cc]);
  } else {            // w_in pack: tile (nt<64, kt<8)
    const int kt = tile & 7, nt = tile >> 3;
#pragma unroll
    for (int j = 0; j < 8; ++j)
      v[j] = f2bf(w[(kt * 32 + gg * 8 + j) * 1024 + nt * 16 + cc]);
  }
  *reinterpret_cast<short8*>(p + ((size_t)region * 262144) + gid * 8) = v;
}

// ---- fused main kernel ----
// NT token tiles of 16; tokens t = a*16 + r. GRP = norm-group size over tiles
// (GRP==NT for deg>0 where a=mm; GRP==1 for deg0 at 32 rows where a=row-block).
// LDS XOR swizzle: byte ^= (t&7)<<4.
template<int NT, int GRP, int OUT_M>
__global__ __launch_bounds__(256, 2)
void ff_se3_kernel(const float* __restrict__ x,
                   const short* __restrict__ wpin,
                   const short* __restrict__ wpout,
                   const float* __restrict__ scale,
                   const float* __restrict__ bias,
                   float* __restrict__ out)
{
  constexpr int T = 16 * NT;                  // tokens per block
  constexpr int R = (OUT_M == 1) ? T : 16;    // output rows per block
  extern __shared__ short lds[];              // T*512 (lA) + 2*T*256 (lH dbuf) bytes
  short* lA  = lds;
  short* lH0 = lds + T * 256;
  short* lH1 = lH0 + T * 128;

  const int tid  = threadIdx.x;
  const int lane = tid & 63;
  const int wave = tid >> 6;
  const int g    = lane >> 4;
  const int lc   = lane & 15;
  const long row0 = (long)blockIdx.x * R;

  // stage x -> lA (nt float4 reads, scatter bf16 into token layout)
  for (int e4 = tid; e4 < R * 64 * OUT_M; e4 += 256) {
    const int r  = e4 / (64 * OUT_M);
    const int o4 = e4 - r * (64 * OUT_M);
    const f32x4 v = __builtin_nontemporal_load(
        reinterpret_cast<const f32x4*>(x + (row0 + r) * (256 * OUT_M) + o4 * 4));
#pragma unroll
    for (int i = 0; i < 4; ++i) {
      const int flat = o4 * 4 + i;
      const int d  = flat / OUT_M;
      const int mm = flat - d * OUT_M;
      const int t  = mm * 16 + r;             // deg0: mm=0 -> t=r (0..31)
      const int byte = t * 512 + ((d * 2) ^ ((t & 7) << 4));
      lA[byte >> 1] = f2bf(v[i]);
    }
  }

  f32x4 acc_out[NT][4];
#pragma unroll
  for (int a = 0; a < NT; ++a)
#pragma unroll
    for (int b = 0; b < 4; ++b) acc_out[a][b] = (f32x4)(0.f);

  __syncthreads();

  for (int c = 0; c < 8; ++c) {   // 128-h chunks
    short* lH = (c & 1) ? lH1 : lH0;

    // scale/bias prefetch (hidden under GEMM1)
    float sc2[2], bi2[2];
#pragma unroll
    for (int nn = 0; nn < 2; ++nn) {
      const int hgl = c * 128 + wave * 32 + nn * 16 + lc;
      sc2[nn] = scale[hgl];
      bi2[nn] = bias[hgl];
    }

    // ---- GEMM1: this wave owns 32 h-cols (2 n-tiles), K=256 ----
    f32x4 acc1[NT][2];
#pragma unroll
    for (int a = 0; a < NT; ++a) { acc1[a][0] = (f32x4)(0.f); acc1[a][1] = (f32x4)(0.f); }
#pragma unroll
    for (int kt = 0; kt < 8; ++kt) {
      short8 af[NT];
#pragma unroll
      for (int a = 0; a < NT; ++a) {
        const int t = a * 16 + lc;
        const int byte = t * 512 + (((kt * 32 + g * 8) * 2) ^ ((t & 7) << 4));
        af[a] = *reinterpret_cast<const short8*>(&lA[byte >> 1]);
      }
      short8 bfr[2];
#pragma unroll
      for (int nn = 0; nn < 2; ++nn) {
        const int ntg = c * 8 + wave * 2 + nn;
        bfr[nn] = *reinterpret_cast<const short8*>(wpin + ((ntg * 8 + kt) * 64 + lane) * 8);
      }
#pragma unroll
      for (int a = 0; a < NT; ++a)
#pragma unroll
        for (int nn = 0; nn < 2; ++nn)
          acc1[a][nn] = __builtin_amdgcn_mfma_f32_16x16x32_bf16(af[a], bfr[nn], acc1[a][nn], 0, 0, 0);
    }

    // ---- prefetch ALL GEMM2 B-frags (in flight across nonlin + barrier) ----
    short8 b2p[4][4];
#pragma unroll
    for (int kk = 0; kk < 4; ++kk)
#pragma unroll
      for (int nn = 0; nn < 4; ++nn) {
        const int tile = (c * 4 + kk) * 16 + wave * 4 + nn;
        b2p[kk][nn] = *reinterpret_cast<const short8*>(wpout + (tile * 64 + lane) * 8);
      }

    // ---- nonlinearity: per-(row,h) norm over its GRP tiles + gelu gate ----
#pragma unroll
    for (int nn = 0; nn < 2; ++nn) {
      const float sc = sc2[nn];
      const float bi = bi2[nn];
#pragma unroll
      for (int reg = 0; reg < 4; ++reg) {
#pragma unroll
        for (int gi = 0; gi < NT / GRP; ++gi) {
          float ns = 0.f;
#pragma unroll
          for (int k = 0; k < GRP; ++k) {
            const float h = acc1[gi * GRP + k][nn][reg];
            ns += h * h;
          }
          ns = fmaxf(ns, 1e-24f);
          const float rn  = __builtin_amdgcn_rsqf(ns);
          const float nrm = ns * rn;
          const float z   = fmaf(nrm, sc, bi);
          float u2 = 2.f * z * fmaf(0.0356774081f * z, z, 0.7978845608f);
          u2 = fminf(u2, 30.f);
          const float e  = __expf(u2);
          const float th = (e - 1.f) * __builtin_amdgcn_rcpf(e + 1.f);
          const float fac = 0.5f * (1.f + th) * z * rn;
          const int tl  = g * 4 + reg;
          const int col = wave * 32 + nn * 16 + lc;
#pragma unroll
          for (int k = 0; k < GRP; ++k) {
            const int a = gi * GRP + k;
            const int t = a * 16 + tl;
            const int byte = t * 256 + ((col * 2) ^ ((t & 7) << 4));
            lH[byte >> 1] = f2bf(acc1[a][nn][reg] * fac);
          }
        }
      }
    }

    __syncthreads();   // the ONLY barrier per chunk

    // ---- GEMM2 partial: acc_out += hg[T,128] @ w_out[chunk,256] ----
#pragma unroll
    for (int kk = 0; kk < 4; ++kk) {
      short8 a2[NT];
#pragma unroll
      for (int a = 0; a < NT; ++a) {
        const int t = a * 16 + lc;
        const int byte = t * 256 + (((kk * 32 + g * 8) * 2) ^ ((t & 7) << 4));
        a2[a] = *reinterpret_cast<const short8*>(&lH[byte >> 1]);
      }
#pragma unroll
      for (int a = 0; a < NT; ++a)
#pragma unroll
        for (int nn = 0; nn < 4; ++nn)
          acc_out[a][nn] = __builtin_amdgcn_mfma_f32_16x16x32_bf16(a2[a], b2p[kk][nn], acc_out[a][nn], 0, 0, 0);
    }
    // next chunk's nonlin writes the OTHER lH buffer -> no second barrier.
  }

  // ---- epilogue: scatter acc to LDS fp32 (exactly T*256 floats), flat copy ----
  __syncthreads();                       // all GEMM2(7) lH reads done
  float* ldsF = reinterpret_cast<float*>(lds);
  constexpr int RW = 256 * OUT_M;        // floats per output row
  if constexpr (OUT_M == 1) {
#pragma unroll
    for (int a = 0; a < NT; ++a)
#pragma unroll
      for (int nn = 0; nn < 4; ++nn) {
        const int d = wave * 64 + nn * 16 + lc;
#pragma unroll
        for (int reg = 0; reg < 4; ++reg) {
          const int t = a * 16 + g * 4 + reg;
          ldsF[t * RW + d] = acc_out[a][nn][reg];
        }
      }
  } else {
#pragma unroll
    for (int mm = 0; mm < NT; ++mm)
#pragma unroll
      for (int nn = 0; nn < 4; ++nn) {
        const int d = wave * 64 + nn * 16 + lc;
#pragma unroll
        for (int reg = 0; reg < 4; ++reg) {
          const int r = g * 4 + reg;
          ldsF[r * RW + d * OUT_M + mm] = acc_out[mm][nn][reg];
        }
      }
  }
  __syncthreads();
  // block tile is contiguous in out: rows [row0, row0+R) -> R*RW floats
  float* obase = out + row0 * RW;
  constexpr int NF4 = (R * RW) / 4;
  for (int i = tid; i < NF4; i += 256) {
    const f32x4 v = *reinterpret_cast<const f32x4*>(&ldsF[i * 4]);
    __builtin_nontemporal_store(v, reinterpret_cast<f32x4*>(obase) + i);
  }
}

extern "C" void kernel_launch(void* const* d_in, const int* in_sizes, int n_in,
                              void* d_out, int out_size, void* d_ws, size_t ws_size,
                              hipStream_t stream)
{
  // d_in order per setup_inputs: (x, w_in, scale, bias, w_out) x degree 0..2
  short* ws = (short*)d_ws;                 // 6 * 512KB = 3MB
  const size_t WSZ = 262144;                // shorts per packed matrix
  float* outf = (float*)d_out;
  const size_t out_off[3] = {0, 4194304, 16777216};  // y0|y1|y2 concat (m=1,3,5)

  pack_all_k<<<768, 256, 0, stream>>>(
      (const float*)d_in[1],  (const float*)d_in[4],
      (const float*)d_in[6],  (const float*)d_in[9],
      (const float*)d_in[11], (const float*)d_in[14], ws);

  for (int dg = 0; dg < 3; ++dg) {
    const float* x  = (const float*)d_in[5 * dg + 0];
    const float* sc = (const float*)d_in[5 * dg + 2];
    const float* bi = (const float*)d_in[5 * dg + 3];
    const short* pin  = ws + (2 * dg) * WSZ;
    const short* pout = ws + (2 * dg + 1) * WSZ;
    float* o = outf + out_off[dg];
    switch (dg) {
      case 0:  // m=1: 32 rows/block, 2 tiles, per-tile norm; LDS 32 KB
        ff_se3_kernel<2, 1, 1><<<512, 256, 32768, stream>>>(x, pin, pout, sc, bi, o);
        break;
      case 1:  // m=3: LDS 48 KB (3 blocks/CU)
        ff_se3_kernel<3, 3, 3><<<1024, 256, 49152, stream>>>(x, pin, pout, sc, bi, o);
        break;
      case 2:  // m=5: LDS 80 KB (2 blocks/CU)
        ff_se3_kernel<5, 5, 5><<<1024, 256, 81920, stream>>>(x, pin, pout, sc, bi, o);
        break;
    }
  }
}

// Round 7
// 231.580 us; speedup vs baseline: 2.7651x; 1.1519x over previous
//
#include <hip/hip_runtime.h>
#include <hip/hip_bf16.h>

// Fused SE(3) feedforward, bf16 MFMA, fp32 accumulate.
// Round 7: 8-wave (512-thread) blocks, same 16-row tile & LDS -> 2x waves/SIMD
// (4 for M=5). Per-wave: GEMM1 owns 16 h-cols, GEMM2 owns 32 d-cols.
// R6's proven 1-barrier/chunk lH double-buffer schedule unchanged.

typedef __attribute__((ext_vector_type(8))) short short8;   // 8 bf16 (MFMA A/B frag)
typedef __attribute__((ext_vector_type(4))) float f32x4;    // MFMA C/D frag

static __device__ __forceinline__ short f2bf(float f) {
  __hip_bfloat16 h = __float2bfloat16(f);
  return *reinterpret_cast<short*>(&h);
}

// ---- fused weight packing into MFMA-fragment order (bf16) ----
// region r = blockIdx.x>>7: r=2*dg+0 -> w_in(dg), r=2*dg+1 -> w_out(dg).
__global__ void pack_all_k(const float* __restrict__ w0i, const float* __restrict__ w0o,
                           const float* __restrict__ w1i, const float* __restrict__ w1o,
                           const float* __restrict__ w2i, const float* __restrict__ w2o,
                           short* __restrict__ p) {
  const int region = blockIdx.x >> 7;                 // 0..5
  const int gid = (blockIdx.x & 127) * 256 + threadIdx.x;  // 0..32767
  const int lane = gid & 63;
  const int tile = gid >> 6;
  const int gg = lane >> 4, cc = lane & 15;
  const float* w = (region == 0) ? w0i : (region == 1) ? w0o :
                   (region == 2) ? w1i : (region == 3) ? w1o :
                   (region == 4) ? w2i : w2o;
  short8 v;
  if (region & 1) {   // w_out pack: tile (kt2<32, nt2<16)
    const int nt2 = tile & 15, kt2 = tile >> 4;
#pragma unroll
    for (int j = 0; j < 8; ++j)
      v[j] = f2bf(w[(kt2 * 32 + gg * 8 + j) * 256 + nt2 * 16 + cc]);
  } else {            // w_in pack: tile (nt<64, kt<8)
    const int kt = tile & 7, nt = tile >> 3;
#pragma unroll
    for (int j = 0; j < 8; ++j)
      v[j] = f2bf(w[(kt * 32 + gg * 8 + j) * 1024 + nt * 16 + cc]);
  }
  *reinterpret_cast<short8*>(p + ((size_t)region * 262144) + gid * 8) = v;
}

// ---- fused main kernel (8 waves) ----
// NT token tiles of 16; tokens t = a*16 + r. GRP = norm-group size over tiles
// (GRP==NT for deg>0 where a=mm; GRP==1 for deg0 at 32 rows).
// LDS XOR swizzle: byte ^= (t&7)<<4.
template<int NT, int GRP, int OUT_M>
__global__ __launch_bounds__(512, 4)
void ff_se3_kernel(const float* __restrict__ x,
                   const short* __restrict__ wpin,
                   const short* __restrict__ wpout,
                   const float* __restrict__ scale,
                   const float* __restrict__ bias,
                   float* __restrict__ out)
{
  constexpr int T = 16 * NT;                  // tokens per block
  constexpr int R = (OUT_M == 1) ? T : 16;    // output rows per block
  extern __shared__ short lds[];              // T*512 (lA) + 2*T*256 (lH dbuf) bytes
  short* lA  = lds;
  short* lH0 = lds + T * 256;
  short* lH1 = lH0 + T * 128;

  const int tid  = threadIdx.x;
  const int lane = tid & 63;
  const int wave = tid >> 6;                  // 0..7
  const int g    = lane >> 4;
  const int lc   = lane & 15;
  const long row0 = (long)blockIdx.x * R;

  // stage x -> lA (nt float4 reads, scatter bf16 into token layout)
  for (int e4 = tid; e4 < R * 64 * OUT_M; e4 += 512) {
    const int r  = e4 / (64 * OUT_M);
    const int o4 = e4 - r * (64 * OUT_M);
    const f32x4 v = __builtin_nontemporal_load(
        reinterpret_cast<const f32x4*>(x + (row0 + r) * (256 * OUT_M) + o4 * 4));
#pragma unroll
    for (int i = 0; i < 4; ++i) {
      const int flat = o4 * 4 + i;
      const int d  = flat / OUT_M;
      const int mm = flat - d * OUT_M;
      const int t  = mm * 16 + r;             // deg0: mm=0 -> t=r
      const int byte = t * 512 + ((d * 2) ^ ((t & 7) << 4));
      lA[byte >> 1] = f2bf(v[i]);
    }
  }

  f32x4 acc_out[NT][2];                       // wave owns 32 d-cols (2 n-tiles)
#pragma unroll
  for (int a = 0; a < NT; ++a) { acc_out[a][0] = (f32x4)(0.f); acc_out[a][1] = (f32x4)(0.f); }

  __syncthreads();

  for (int c = 0; c < 8; ++c) {   // 128-h chunks
    short* lH = (c & 1) ? lH1 : lH0;

    // scale/bias prefetch (hidden under GEMM1); wave owns cols [wave*16, +16)
    const int hgl = c * 128 + wave * 16 + lc;
    const float sc = scale[hgl];
    const float bi = bias[hgl];

    // ---- GEMM1: wave owns 16 h-cols (1 n-tile), K=256 ----
    f32x4 acc1[NT];
#pragma unroll
    for (int a = 0; a < NT; ++a) acc1[a] = (f32x4)(0.f);
#pragma unroll
    for (int kt = 0; kt < 8; ++kt) {
      short8 af[NT];
#pragma unroll
      for (int a = 0; a < NT; ++a) {
        const int t = a * 16 + lc;
        const int byte = t * 512 + (((kt * 32 + g * 8) * 2) ^ ((t & 7) << 4));
        af[a] = *reinterpret_cast<const short8*>(&lA[byte >> 1]);
      }
      const int ntg = c * 8 + wave;
      const short8 bfr = *reinterpret_cast<const short8*>(wpin + ((ntg * 8 + kt) * 64 + lane) * 8);
#pragma unroll
      for (int a = 0; a < NT; ++a)
        acc1[a] = __builtin_amdgcn_mfma_f32_16x16x32_bf16(af[a], bfr, acc1[a], 0, 0, 0);
    }

    // ---- prefetch GEMM2 B-frags (in flight across nonlin + barrier) ----
    short8 b2p[4][2];
#pragma unroll
    for (int kk = 0; kk < 4; ++kk)
#pragma unroll
      for (int nn = 0; nn < 2; ++nn) {
        const int tile = (c * 4 + kk) * 16 + wave * 2 + nn;
        b2p[kk][nn] = *reinterpret_cast<const short8*>(wpout + (tile * 64 + lane) * 8);
      }

    // ---- nonlinearity: per-(row,h) norm over its GRP tiles + gelu gate ----
#pragma unroll
    for (int reg = 0; reg < 4; ++reg) {
#pragma unroll
      for (int gi = 0; gi < NT / GRP; ++gi) {
        float ns = 0.f;
#pragma unroll
        for (int k = 0; k < GRP; ++k) {
          const float h = acc1[gi * GRP + k][reg];
          ns += h * h;
        }
        ns = fmaxf(ns, 1e-24f);
        const float rn  = __builtin_amdgcn_rsqf(ns);
        const float nrm = ns * rn;
        const float z   = fmaf(nrm, sc, bi);
        float u2 = 2.f * z * fmaf(0.0356774081f * z, z, 0.7978845608f);
        u2 = fminf(u2, 30.f);
        const float e  = __expf(u2);
        const float th = (e - 1.f) * __builtin_amdgcn_rcpf(e + 1.f);
        const float fac = 0.5f * (1.f + th) * z * rn;
        const int tl  = g * 4 + reg;
        const int col = wave * 16 + lc;
#pragma unroll
        for (int k = 0; k < GRP; ++k) {
          const int a = gi * GRP + k;
          const int t = a * 16 + tl;
          const int byte = t * 256 + ((col * 2) ^ ((t & 7) << 4));
          lH[byte >> 1] = f2bf(acc1[a][reg] * fac);
        }
      }
    }

    __syncthreads();   // the ONLY barrier per chunk

    // ---- GEMM2 partial: wave owns d-cols [wave*32, +32) ----
#pragma unroll
    for (int kk = 0; kk < 4; ++kk) {
      short8 a2[NT];
#pragma unroll
      for (int a = 0; a < NT; ++a) {
        const int t = a * 16 + lc;
        const int byte = t * 256 + (((kk * 32 + g * 8) * 2) ^ ((t & 7) << 4));
        a2[a] = *reinterpret_cast<const short8*>(&lH[byte >> 1]);
      }
#pragma unroll
      for (int a = 0; a < NT; ++a)
#pragma unroll
        for (int nn = 0; nn < 2; ++nn)
          acc_out[a][nn] = __builtin_amdgcn_mfma_f32_16x16x32_bf16(a2[a], b2p[kk][nn], acc_out[a][nn], 0, 0, 0);
    }
    // next chunk's nonlin writes the OTHER lH buffer -> no second barrier.
  }

  // ---- epilogue: scatter acc to LDS fp32 (exactly T*256 floats), flat copy ----
  __syncthreads();                       // all GEMM2(7) lH reads done
  float* ldsF = reinterpret_cast<float*>(lds);
  constexpr int RW = 256 * OUT_M;        // floats per output row
  if constexpr (OUT_M == 1) {
#pragma unroll
    for (int a = 0; a < NT; ++a)
#pragma unroll
      for (int nn = 0; nn < 2; ++nn) {
        const int d = wave * 32 + nn * 16 + lc;
#pragma unroll
        for (int reg = 0; reg < 4; ++reg) {
          const int t = a * 16 + g * 4 + reg;
          ldsF[t * RW + d] = acc_out[a][nn][reg];
        }
      }
  } else {
#pragma unroll
    for (int mm = 0; mm < NT; ++mm)
#pragma unroll
      for (int nn = 0; nn < 2; ++nn) {
        const int d = wave * 32 + nn * 16 + lc;
#pragma unroll
        for (int reg = 0; reg < 4; ++reg) {
          const int r = g * 4 + reg;
          ldsF[r * RW + d * OUT_M + mm] = acc_out[mm][nn][reg];
        }
      }
  }
  __syncthreads();
  // block tile is contiguous in out: rows [row0, row0+R) -> R*RW floats
  float* obase = out + row0 * RW;
  constexpr int NF4 = (R * RW) / 4;
  for (int i = tid; i < NF4; i += 512) {
    const f32x4 v = *reinterpret_cast<const f32x4*>(&ldsF[i * 4]);
    __builtin_nontemporal_store(v, reinterpret_cast<f32x4*>(obase) + i);
  }
}

extern "C" void kernel_launch(void* const* d_in, const int* in_sizes, int n_in,
                              void* d_out, int out_size, void* d_ws, size_t ws_size,
                              hipStream_t stream)
{
  // d_in order per setup_inputs: (x, w_in, scale, bias, w_out) x degree 0..2
  short* ws = (short*)d_ws;                 // 6 * 512KB = 3MB
  const size_t WSZ = 262144;                // shorts per packed matrix
  float* outf = (float*)d_out;
  const size_t out_off[3] = {0, 4194304, 16777216};  // y0|y1|y2 concat (m=1,3,5)

  pack_all_k<<<768, 256, 0, stream>>>(
      (const float*)d_in[1],  (const float*)d_in[4],
      (const float*)d_in[6],  (const float*)d_in[9],
      (const float*)d_in[11], (const float*)d_in[14], ws);

  for (int dg = 0; dg < 3; ++dg) {
    const float* x  = (const float*)d_in[5 * dg + 0];
    const float* sc = (const float*)d_in[5 * dg + 2];
    const float* bi = (const float*)d_in[5 * dg + 3];
    const short* pin  = ws + (2 * dg) * WSZ;
    const short* pout = ws + (2 * dg + 1) * WSZ;
    float* o = outf + out_off[dg];
    switch (dg) {
      case 0:  // m=1: 32 rows/block; LDS 32 KB
        ff_se3_kernel<2, 1, 1><<<512, 512, 32768, stream>>>(x, pin, pout, sc, bi, o);
        break;
      case 1:  // m=3: LDS 48 KB
        ff_se3_kernel<3, 3, 3><<<1024, 512, 49152, stream>>>(x, pin, pout, sc, bi, o);
        break;
      case 2:  // m=5: LDS 80 KB (2 blocks/CU, 16 waves/CU)
        ff_se3_kernel<5, 5, 5><<<1024, 512, 81920, stream>>>(x, pin, pout, sc, bi, o);
        break;
    }
  }
}